// Round 21
// baseline (1111.617 us; speedup 1.0000x reference)
//
#include <hip/hip_runtime.h>
#include <hip/hip_bf16.h>
#include <cmath>

constexpr int T_ = 64, B_ = 128, S_ = 128, H_ = 200, E_ = 200, A_ = 100, V_ = 10003;
constexpr int KP = 224;        // padded K (=H/E), multiple of 32
constexpr int VP = 10240;      // padded V, multiple of 256
constexpr int MROWS = T_ * B_; // 8192 rows in the batched GEMMs
constexpr int NCB = VP / 256;  // 40 column-blocks
constexpr int G3 = 3 * H_;     // 600 gate rows
constexpr int EH = E_ + H_;    // 400
constexpr int ELD = 136;       // encLh row stride in f16 (16B-aligned)
constexpr int AH2P = 104;      // padded A for f16 ah2 rows (13 x 8)
constexpr int NP = 768;        // padded col count for [Wih_e | W3] fragment pack
constexpr int NP2 = 128;       // padded col count for W2 fragment pack
constexpr int NTH = 512;       // k_recur block size (proven 128-VGPR config)
constexpr int NPK = 32;        // spare pack blocks appended to k_recur grid

typedef __attribute__((ext_vector_type(8))) short bf16x8;
typedef __attribute__((ext_vector_type(4))) float f32x4;
typedef __attribute__((ext_vector_type(2))) _Float16 h2;
typedef __attribute__((ext_vector_type(8))) _Float16 h8;

#if __has_builtin(__builtin_amdgcn_fdot2)
__device__ __forceinline__ float fdot2f(h2 a, h2 b, float c) {
  return __builtin_amdgcn_fdot2(a, b, c, false);
}
#else
__device__ __forceinline__ float fdot2f(h2 a, h2 b, float c) {
  return c + (float)a[0] * (float)b[0] + (float)a[1] * (float)b[1];
}
#endif

// Depth-5 software-pipelined 200-length dot (R13 proven: fits 128 VGPRs).
__device__ __forceinline__ float dot200p5(const h8* __restrict__ w, int stride,
                                          const h8* __restrict__ x) {
  const h8* p = w;
  h8 w0 = p[0]; p += stride;
  h8 w1 = p[0]; p += stride;
  h8 w2 = p[0]; p += stride;
  h8 w3 = p[0]; p += stride;
  h8 w4 = p[0]; p += stride;
  float a0 = 0.f, a1 = 0.f, a2 = 0.f, a3 = 0.f;
#define DOT_CONSUME(WREG, K)                    \
  {                                             \
    h8 xv = x[K];                               \
    h2 wp[4], xp[4];                            \
    __builtin_memcpy(wp, &WREG, 16);            \
    __builtin_memcpy(xp, &xv, 16);              \
    a0 = fdot2f(wp[0], xp[0], a0);              \
    a1 = fdot2f(wp[1], xp[1], a1);              \
    a2 = fdot2f(wp[2], xp[2], a2);              \
    a3 = fdot2f(wp[3], xp[3], a3);              \
  }
#define DOT_RELOAD(WREG) { WREG = p[0]; p += stride; }
  DOT_CONSUME(w0, 0)  DOT_RELOAD(w0)
  DOT_CONSUME(w1, 1)  DOT_RELOAD(w1)
  DOT_CONSUME(w2, 2)  DOT_RELOAD(w2)
  DOT_CONSUME(w3, 3)  DOT_RELOAD(w3)
  DOT_CONSUME(w4, 4)  DOT_RELOAD(w4)
  DOT_CONSUME(w0, 5)  DOT_RELOAD(w0)
  DOT_CONSUME(w1, 6)  DOT_RELOAD(w1)
  DOT_CONSUME(w2, 7)  DOT_RELOAD(w2)
  DOT_CONSUME(w3, 8)  DOT_RELOAD(w3)
  DOT_CONSUME(w4, 9)  DOT_RELOAD(w4)
  DOT_CONSUME(w0, 10) DOT_RELOAD(w0)
  DOT_CONSUME(w1, 11) DOT_RELOAD(w1)
  DOT_CONSUME(w2, 12) DOT_RELOAD(w2)
  DOT_CONSUME(w3, 13) DOT_RELOAD(w3)
  DOT_CONSUME(w4, 14) DOT_RELOAD(w4)
  DOT_CONSUME(w0, 15) DOT_RELOAD(w0)
  DOT_CONSUME(w1, 16) DOT_RELOAD(w1)
  DOT_CONSUME(w2, 17) DOT_RELOAD(w2)
  DOT_CONSUME(w3, 18) DOT_RELOAD(w3)
  DOT_CONSUME(w4, 19) DOT_RELOAD(w4)
  DOT_CONSUME(w0, 20)
  DOT_CONSUME(w1, 21)
  DOT_CONSUME(w2, 22)
  DOT_CONSUME(w3, 23)
  DOT_CONSUME(w4, 24)
#undef DOT_CONSUME
#undef DOT_RELOAD
  return (a0 + a1) + (a2 + a3);
}

// ---------------- precompute kernels ----------------

// Small f16/bf16 packs needed BEFORE k_recur / k_genc / k_gemb; zero ah2h pad.
__global__ __launch_bounds__(256) void k_pack(const float* __restrict__ W1,
                                              const float* __restrict__ Wih,
                                              const float* __restrict__ Whh,
                                              const float* __restrict__ W3,
                                              const float* __restrict__ W2,
                                              _Float16* __restrict__ W1h,
                                              _Float16* __restrict__ Wihh,
                                              _Float16* __restrict__ Whhh,
                                              __hip_bfloat16* __restrict__ wep,
                                              __hip_bfloat16* __restrict__ w2p,
                                              _Float16* __restrict__ ah2h) {
  const int stride = gridDim.x * blockDim.x;
  const int tid0 = blockIdx.x * blockDim.x + threadIdx.x;
  for (int idx = tid0; idx < 25 * A_ * 8; idx += stride) {
    int kk = idx & 7, a = (idx >> 3) % A_, k8 = idx / (8 * A_);
    W1h[idx] = (_Float16)W1[(size_t)a * H_ + k8 * 8 + kk];
  }
  for (int idx = tid0; idx < 50 * G3 * 8; idx += stride) {
    int kk = idx & 7, n = (idx >> 3) % G3, k8 = idx / (8 * G3);
    Wihh[idx] = (_Float16)Wih[(size_t)n * EH + k8 * 8 + kk];
  }
  for (int idx = tid0; idx < 25 * G3 * 8; idx += stride) {
    int kk = idx & 7, n = (idx >> 3) % G3, k8 = idx / (8 * G3);
    Whhh[idx] = (_Float16)Whh[(size_t)n * H_ + k8 * 8 + kk];
  }
  // WEP: [KP/8][NP][8] bf16 pack of [Wih_e (600) | W3 (100) | pad]
  for (int idx = tid0; idx < (KP / 8) * NP * 8; idx += stride) {
    int kk = idx & 7, c = (idx >> 3) % NP, k8 = idx / (8 * NP);
    int k = k8 * 8 + kk;
    float v = 0.f;
    if (k < E_) {
      if (c < G3) v = Wih[(size_t)c * EH + k];           // xe-half of Wih
      else if (c < G3 + A_) v = W3[(size_t)(c - G3) * E_ + k];
    }
    wep[idx] = __float2bfloat16(v);
  }
  // W2P: [KP/8][NP2][8] bf16 pack of W2 (100 rows)
  for (int idx = tid0; idx < (KP / 8) * NP2 * 8; idx += stride) {
    int kk = idx & 7, c = (idx >> 3) % NP2, k8 = idx / (8 * NP2);
    int k = k8 * 8 + kk;
    float v = (k < H_ && c < A_) ? W2[(size_t)c * H_ + k] : 0.f;
    w2p[idx] = __float2bfloat16(v);
  }
  // zero ah2h pad columns [A_, AH2P)
  for (int idx = tid0; idx < B_ * S_ * (AH2P - A_); idx += stride) {
    int row = idx / (AH2P - A_), col = A_ + idx % (AH2P - A_);
    ah2h[(size_t)row * AH2P + col] = (_Float16)0.f;
  }
}

// MFMA GEMM: ah2h = enc @ W2^T + b2 (f16 out, (b,s)-transposed write).
__global__ __launch_bounds__(256) void k_genc(const float* __restrict__ encoder,
                                              const short* __restrict__ w2p,
                                              const float* __restrict__ b2,
                                              _Float16* __restrict__ ah2h) {
  constexpr int ALD = 232;
  __shared__ __align__(16) __hip_bfloat16 aL[128 * ALD]; // 59.4 KB
  const int tid = threadIdx.x;
  const int w = tid >> 6, l = tid & 63, lm = l & 15, lg = l >> 4;
  const int r0 = blockIdx.y * 128;
  const int rloc = (w >> 1) * 64;
  const int v0 = (w & 1) * 64;

  for (int i = tid; i < 128 * KP; i += 256) {
    int row = i / KP, k = i - row * KP;
    float v = (k < H_) ? encoder[(size_t)(r0 + row) * H_ + k] : 0.f;
    aL[row * ALD + k] = __float2bfloat16(v);
  }
  __syncthreads();

  f32x4 acc[4][4] = {};
#pragma unroll
  for (int kt = 0; kt < KP / 32; ++kt) {
    const int k0 = kt * 32;
    bf16x8 af[4], bfr[4];
#pragma unroll
    for (int wm = 0; wm < 4; ++wm)
      af[wm] = *(const bf16x8*)(aL + (rloc + wm * 16 + lm) * ALD + k0 + lg * 8);
#pragma unroll
    for (int n = 0; n < 4; ++n)
      bfr[n] = *(const bf16x8*)(w2p + ((size_t)((k0 >> 3) + lg) * NP2 + v0 + n * 16 + lm) * 8);
#pragma unroll
    for (int wm = 0; wm < 4; ++wm)
#pragma unroll
      for (int n = 0; n < 4; ++n)
        acc[wm][n] = __builtin_amdgcn_mfma_f32_16x16x32_bf16(af[wm], bfr[n], acc[wm][n], 0, 0, 0);
  }

#pragma unroll
  for (int n = 0; n < 4; ++n) {
    const int vv = v0 + n * 16 + lm;
    if (vv >= A_) continue;
    const float bias = b2[vv];
#pragma unroll
    for (int wm = 0; wm < 4; ++wm) {
#pragma unroll
      for (int j = 0; j < 4; ++j) {
        const int grow = r0 + rloc + wm * 16 + lg * 4 + j; // = s*B + b
        const int bb = grow & (B_ - 1);
        const int ss = grow >> 7;
        ah2h[((size_t)bb * S_ + ss) * AH2P + vv] = (_Float16)(acc[wm][n][j] + bias);
      }
    }
  }
}

// MFMA GEMM over gathered emb rows: [giX | ah3] = emb[tok[r]] @ [Wih_e | W3]^T + bias
__global__ __launch_bounds__(256) void k_gemb(const int* __restrict__ tokens,
                                              const float* __restrict__ emb,
                                              const short* __restrict__ wep,
                                              const float* __restrict__ bih,
                                              const float* __restrict__ b3,
                                              float* __restrict__ giX,
                                              float* __restrict__ ah3) {
  constexpr int ALD = 232;
  __shared__ __align__(16) __hip_bfloat16 aL[64 * ALD];
  __shared__ int tokL[64];
  const int tid = threadIdx.x;
  const int w = tid >> 6, l = tid & 63, lm = l & 15, lg = l >> 4;
  const int r0 = blockIdx.y * 64;
  const int v0 = blockIdx.x * 256 + w * 64;

  if (tid < 64) tokL[tid] = tokens[r0 + tid];
  __syncthreads();
  for (int i = tid; i < 64 * KP; i += 256) {
    int row = i / KP, k = i - row * KP;
    float v = (k < E_) ? emb[(size_t)tokL[row] * E_ + k] : 0.f;
    aL[row * ALD + k] = __float2bfloat16(v);
  }
  __syncthreads();

  f32x4 acc[4][4] = {};
#pragma unroll
  for (int kt = 0; kt < KP / 32; ++kt) {
    const int k0 = kt * 32;
    bf16x8 af[4], bfr[4];
#pragma unroll
    for (int wm = 0; wm < 4; ++wm)
      af[wm] = *(const bf16x8*)(aL + (wm * 16 + lm) * ALD + k0 + lg * 8);
#pragma unroll
    for (int n = 0; n < 4; ++n)
      bfr[n] = *(const bf16x8*)(wep + ((size_t)((k0 >> 3) + lg) * NP + v0 + n * 16 + lm) * 8);
#pragma unroll
    for (int wm = 0; wm < 4; ++wm)
#pragma unroll
      for (int n = 0; n < 4; ++n)
        acc[wm][n] = __builtin_amdgcn_mfma_f32_16x16x32_bf16(af[wm], bfr[n], acc[wm][n], 0, 0, 0);
  }

#pragma unroll
  for (int n = 0; n < 4; ++n) {
    const int vv = v0 + n * 16 + lm;
    const bool isGi = vv < G3;
    const bool isA3 = !isGi && vv < G3 + A_;
    const float bias = isGi ? bih[vv] : (isA3 ? b3[vv - G3] : 0.f);
#pragma unroll
    for (int wm = 0; wm < 4; ++wm) {
#pragma unroll
      for (int j = 0; j < 4; ++j) {
        const int row = r0 + wm * 16 + lg * 4 + j;
        const float val = acc[wm][n][j] + bias;
        if (isGi) giX[(size_t)row * G3 + vv] = val;
        else if (isA3) ah3[(size_t)row * A_ + (vv - G3)] = val;
      }
    }
  }
}

// ---------------- persistent recurrence kernel (R15 compute, 512 threads) ----
__global__ __launch_bounds__(NTH) void k_recur(const float* __restrict__ hidden0,
                                               const _Float16* __restrict__ ah2h,
                                               const float* __restrict__ ah3,
                                               const float* __restrict__ encoder,
                                               const _Float16* __restrict__ W1h,
                                               const float* __restrict__ b1,
                                               const float* __restrict__ attn_W,
                                               const float* __restrict__ attn_b,
                                               const _Float16* __restrict__ Wihh,
                                               const _Float16* __restrict__ Whhh,
                                               const float* __restrict__ bhh,
                                               const float* __restrict__ giX,
                                               const float* __restrict__ outW,
                                               __hip_bfloat16* __restrict__ wpk,
                                               __hip_bfloat16* __restrict__ hall,
                                               float* __restrict__ out_hidden,
                                               float* __restrict__ out_attn) {
  __shared__ __align__(16) _Float16 encLh[H_ * ELD]; // [h][s] f16, 54.4 KB
  __shared__ __align__(16) h2 h16[100];
  __shared__ __align__(16) h2 xch[100];
  __shared__ __align__(16) h2 aLh[64];
  __shared__ float s1[AH2P];
  __shared__ float aW[AH2P];
  __shared__ float red[8];
  __shared__ float giL[G3];    // step-t giX row, prefetched in phase 3
  __shared__ float part[1200]; // [0,600): h.Whh | [600,1200): xc.Wih_c

  const int b = blockIdx.x, tid = threadIdx.x;
  const int lane = tid & 63;

  if (b >= B_) {
    const int pt = (b - B_) * NTH + tid;
    const int pstride = NPK * NTH;
    const int total = (KP / 8) * VP * 8;
    for (int idx = pt; idx < total; idx += pstride) {
      int kk = idx & 7;
      int v = (idx >> 3) % VP;
      int kb = idx / (8 * VP);
      int k = kb * 8 + kk;
      float val = (k < H_ && v < V_) ? outW[(size_t)v * H_ + k] : 0.f;
      wpk[idx] = __float2bfloat16(val);
    }
    const __hip_bfloat16 z = __float2bfloat16(0.f);
    for (int idx = pt; idx < MROWS * (KP - H_); idx += pstride) {
      int row = idx / (KP - H_), col = H_ + idx % (KP - H_);
      hall[(size_t)row * KP + col] = z;
    }
    return;
  }

  // ---- one-time init ----
  for (int i = tid; i < S_ * H_; i += NTH) {
    int s = i / H_, h = i - s * H_;
    encLh[h * ELD + s] = (_Float16)encoder[((size_t)s * B_ + b) * H_ + h];
  }
  float hreg = 0.f, bhr = 0.f, bhz = 0.f, bhn = 0.f;
  if (tid < H_) {
    hreg = hidden0[b * H_ + tid];
    bhr = bhh[tid]; bhz = bhh[200 + tid]; bhn = bhh[400 + tid];
  }
  if (tid < 100) {
    h2 v;
    v[0] = (_Float16)hidden0[b * H_ + 2 * tid];
    v[1] = (_Float16)hidden0[b * H_ + 2 * tid + 1];
    h16[tid] = v;
  }
  for (int i = tid; i < AH2P; i += NTH) {
    aW[i] = (i < A_) ? attn_W[i] : 0.f;
    s1[i] = 0.f;
  }
  h8 ah2row[13]; // b-row of ah2 at s=tid, t-invariant; registers (tid<128 only)
  if (tid < S_) {
    const h8* src = (const h8*)(ah2h + ((size_t)b * S_ + tid) * AH2P);
#pragma unroll
    for (int r = 0; r < 13; ++r) ah2row[r] = src[r];
  }
  const float ab = attn_b[0];
  __syncthreads();

  const h8* W1h8 = (const h8*)W1h;
  const h8* Wihc8 = (const h8*)Wihh + (size_t)25 * G3; // xc-half: k8 in [25,50)
  const h8* Whhh8 = (const h8*)Whhh;

  for (int t = 0; t < T_; ++t) {
    const h8* xs = (const h8*)h16;
    // ---- phase 1: 700 units = 100 s1-dots + 600 gh-dots (interleaved u-loop)
    for (int u = tid; u < 700; u += NTH) {
      if (u < 100) {
        const float ah3A = ah3[((size_t)t * B_ + b) * A_ + u]; // early loads
        const float b1A = b1[u];
        s1[u] = dot200p5(W1h8 + u, A_, xs) + b1A + ah3A;
      } else {
        const int g = u - 100;
        part[g] = dot200p5(Whhh8 + g, G3, xs);
      }
    }
    __syncthreads();

    // ---- phase 2: relu-attn logits + flash-merged softmax (tid<128)
    float evw = 0.f;
    const int w01 = tid >> 6;
    if (tid < S_) {
      float acc = ab;
#pragma unroll
      for (int r = 0; r < 13; ++r) {
        h8 w = ah2row[r];
#pragma unroll
        for (int j = 0; j < 8; ++j) {
          const int a = r * 8 + j;
          acc += fmaxf(s1[a] + (float)w[j], 0.f) * aW[a];
        }
      }
      float m = acc;
#pragma unroll
      for (int off = 32; off > 0; off >>= 1) m = fmaxf(m, __shfl_xor(m, off, 64));
      evw = expf(acc - m);
      float sm = evw;
#pragma unroll
      for (int off = 32; off > 0; off >>= 1) sm += __shfl_xor(sm, off, 64);
      if (lane == 0) { red[w01] = m; red[4 + w01] = sm; }
    }
    __syncthreads();
    if (tid < S_) {
      const float m0 = red[0], m1 = red[1];
      const float M = fmaxf(m0, m1);
      const float SS = red[4] * expf(m0 - M) + red[5] * expf(m1 - M);
      const float av = evw * expf((w01 ? m1 : m0) - M) / SS;
      out_attn[((size_t)t * B_ + b) * S_ + tid] = av;
      const float avn = __shfl_xor(av, 1, 64);
      if ((tid & 1) == 0) {
        h2 v; v[0] = (_Float16)av; v[1] = (_Float16)avn;
        aLh[tid >> 1] = v;
      }
    }
    __syncthreads();

    // ---- phase 3: ctx (tid<200) || giX prefetch -> LDS (tid>=200)
    if (tid < H_) {
      const h8* er = (const h8*)(encLh + tid * ELD);
      float c0 = 0.f, c1 = 0.f, c2 = 0.f, c3 = 0.f;
#pragma unroll
      for (int k8 = 0; k8 < 16; ++k8) {
        h8 evv = er[k8];
        h2 ep[4];
        __builtin_memcpy(ep, &evv, 16);
        c0 = fdot2f(ep[0], aLh[4 * k8 + 0], c0);
        c1 = fdot2f(ep[1], aLh[4 * k8 + 1], c1);
        c2 = fdot2f(ep[2], aLh[4 * k8 + 2], c2);
        c3 = fdot2f(ep[3], aLh[4 * k8 + 3], c3);
      }
      const float c = (c0 + c1) + (c2 + c3);
      const float cn = __shfl_xor(c, 1, 64);
      if ((tid & 1) == 0) {
        h2 v; v[0] = (_Float16)c; v[1] = (_Float16)cn;
        xch[tid >> 1] = v;
      }
    } else {
      const int j = tid - 200; // 312 threads cover 300 float2
      if (j < 300) {
        float2 g2 = ((const float2*)(giX + ((size_t)t * B_ + b) * G3))[j];
        giL[2 * j] = g2.x;
        giL[2 * j + 1] = g2.y;
      }
    }
    __syncthreads();

    // ---- phase 4: gi_xc (600 units, interleaved u-loop)
    {
      const h8* xc8 = (const h8*)xch;
      for (int u = tid; u < 600; u += NTH) {
        part[600 + u] = dot200p5(Wihc8 + u, G3, xc8);
      }
    }
    __syncthreads();

    // ---- phase 5: gates + h update (tid<200); giX partials from LDS
    if (tid < H_) {
      const int n = tid;
      const float gir = giL[n] + part[600 + n];
      const float giz = giL[200 + n] + part[800 + n];
      const float gin = giL[400 + n] + part[1000 + n];
      const float ghr = part[n] + bhr;
      const float ghz = part[200 + n] + bhz;
      const float ghn = part[400 + n] + bhn;
      const float r = 1.f / (1.f + expf(-(gir + ghr)));
      const float z = 1.f / (1.f + expf(-(giz + ghz)));
      const float nn = tanhf(gin + r * ghn);
      const float hv = (1.f - z) * nn + z * hreg;
      hreg = hv;
      hall[((size_t)t * B_ + b) * KP + n] = __float2bfloat16(hv);
      const float hn2 = __shfl_xor(hv, 1, 64);
      if ((n & 1) == 0) {
        h2 v; v[0] = (_Float16)hv; v[1] = (_Float16)hn2;
        h16[n >> 1] = v;
      }
      if (t == T_ - 1) out_hidden[b * H_ + n] = hv;
    }
    __syncthreads();
  }
}

// ---------------- batched output GEMM + log-softmax ----------------
// Single GEMM pass: softmax partials + LDS-staged coalesced write of
// UNNORMALIZED logits (R18's proven epilogue pattern).
__global__ __launch_bounds__(256) void k_big0(const short* __restrict__ hb,
                                              const short* __restrict__ wpk,
                                              const float* __restrict__ outb,
                                              float* __restrict__ pmax,
                                              float* __restrict__ psum,
                                              float* __restrict__ out_logp) {
  const int tid = threadIdx.x;
  const int w = tid >> 6, l = tid & 63;
  const int lm = l & 15, lg = l >> 4;
  const int r0 = blockIdx.y * 64;
  const int v0c = blockIdx.x * 256;
  const int v0 = v0c + w * 64;

  __shared__ float smax[4][64], ssum[4][64];
  __shared__ float tr[32][260]; // 33.3 KB row-staging tile

  f32x4 acc[4][4] = {};
#pragma unroll
  for (int kt = 0; kt < KP / 32; ++kt) {
    const int k0 = kt * 32;
    bf16x8 af[4], bfr[4];
#pragma unroll
    for (int wm = 0; wm < 4; ++wm)
      af[wm] = *(const bf16x8*)(hb + (size_t)(r0 + wm * 16 + lm) * KP + k0 + lg * 8);
#pragma unroll
    for (int n = 0; n < 4; ++n)
      bfr[n] = *(const bf16x8*)(wpk + ((size_t)((k0 >> 3) + lg) * VP + v0 + n * 16 + lm) * 8);
#pragma unroll
    for (int wm = 0; wm < 4; ++wm)
#pragma unroll
      for (int n = 0; n < 4; ++n)
        acc[wm][n] = __builtin_amdgcn_mfma_f32_16x16x32_bf16(af[wm], bfr[n], acc[wm][n], 0, 0, 0);
  }

  int vv[4]; float bias[4]; bool val[4];
#pragma unroll
  for (int n = 0; n < 4; ++n) {
    vv[n] = v0 + n * 16 + lm;
    val[n] = vv[n] < V_;
    bias[n] = val[n] ? outb[vv[n]] : 0.f;
  }

  // softmax partials over this 256-col window
#pragma unroll
  for (int wm = 0; wm < 4; ++wm) {
#pragma unroll
    for (int j = 0; j < 4; ++j) {
      float mv = -INFINITY;
#pragma unroll
      for (int n = 0; n < 4; ++n)
        if (val[n]) mv = fmaxf(mv, acc[wm][n][j] + bias[n]);
      for (int off = 8; off > 0; off >>= 1) mv = fmaxf(mv, __shfl_xor(mv, off, 64));
      float sv = 0.f;
#pragma unroll
      for (int n = 0; n < 4; ++n)
        if (val[n]) sv += expf(acc[wm][n][j] + bias[n] - mv);
      for (int off = 8; off > 0; off >>= 1) sv += __shfl_xor(sv, off, 64);
      if (lm == 0) {
        smax[w][wm * 16 + lg * 4 + j] = mv;
        ssum[w][wm * 16 + lg * 4 + j] = sv;
      }
    }
  }
  __syncthreads();
  if (tid < 64) {
    float mv = -INFINITY;
    for (int ww = 0; ww < 4; ++ww) mv = fmaxf(mv, smax[ww][tid]);
    float sv = 0.f;
    for (int ww = 0; ww < 4; ++ww) {
      float sw = ssum[ww][tid];
      if (sw > 0.f) sv += expf(smax[ww][tid] - mv) * sw;
    }
    pmax[(size_t)blockIdx.x * MROWS + r0 + tid] = mv;
    psum[(size_t)blockIdx.x * MROWS + r0 + tid] = sv;
  }

  // two 32-row halves: stage acc+bias into LDS, coalesced row-major write
#pragma unroll
  for (int half = 0; half < 2; ++half) {
    __syncthreads();
#pragma unroll
    for (int wmi = 0; wmi < 2; ++wmi) {
      const int wm = half * 2 + wmi;
#pragma unroll
      for (int n = 0; n < 4; ++n) {
        const int col = w * 64 + n * 16 + lm;
#pragma unroll
        for (int j = 0; j < 4; ++j)
          tr[wmi * 16 + lg * 4 + j][col] = acc[wm][n][j] + bias[n];
      }
    }
    __syncthreads();
    const int lw = tid & 63;
    const int wv = tid >> 6;
    for (int rr = wv; rr < 32; rr += 4) {
      const int grow = r0 + half * 32 + rr;
      float* dst = out_logp + (size_t)grow * V_;
#pragma unroll
      for (int cc = 0; cc < 4; ++cc) {
        const int col = cc * 64 + lw;
        const int vvx = v0c + col;
        if (vvx < V_) dst[vvx] = tr[rr][col]; // unnormalized
      }
    }
  }
}

__global__ __launch_bounds__(256) void k_lse(const float* __restrict__ pmax,
                                             const float* __restrict__ psum,
                                             float* __restrict__ lse) {
  const int r = blockIdx.x * 256 + threadIdx.x;
  float mv = -INFINITY;
  for (int c = 0; c < NCB; ++c) mv = fmaxf(mv, pmax[(size_t)c * MROWS + r]);
  float sv = 0.f;
  for (int c = 0; c < NCB; ++c) {
    float sw = psum[(size_t)c * MROWS + r];
    if (sw > 0.f) sv += expf(pmax[(size_t)c * MROWS + r] - mv) * sw;
  }
  lse[r] = mv + logf(sv);
}

// normalize: out_logp[row][v] -= lse[row]  (4 rows per block, coalesced stream)
__global__ __launch_bounds__(256) void k_norm(float* __restrict__ out_logp,
                                              const float* __restrict__ lse) {
  const int r0 = blockIdx.x * 4;
#pragma unroll
  for (int rr = 0; rr < 4; ++rr) {
    const int row = r0 + rr;
    const float ls = lse[row];
    float* p = out_logp + (size_t)row * V_;
    for (int v = threadIdx.x; v < V_; v += 256) p[v] -= ls;
  }
}

// ---------------- host launch ----------------

extern "C" void kernel_launch(void* const* d_in, const int* in_sizes, int n_in,
                              void* d_out, int out_size, void* d_ws, size_t ws_size,
                              hipStream_t stream) {
  (void)in_sizes; (void)n_in; (void)out_size; (void)ws_size;
  const int* tokens = (const int*)d_in[0];
  const float* hidden0 = (const float*)d_in[1];
  const float* encoder = (const float*)d_in[2];
  const float* emb = (const float*)d_in[3];
  const float* W1 = (const float*)d_in[4];
  const float* b1 = (const float*)d_in[5];
  const float* W2 = (const float*)d_in[6];
  const float* b2 = (const float*)d_in[7];
  const float* W3 = (const float*)d_in[8];
  const float* b3 = (const float*)d_in[9];
  const float* attn_W = (const float*)d_in[10];
  const float* attn_b = (const float*)d_in[11];
  const float* Wih = (const float*)d_in[12];
  const float* Whh = (const float*)d_in[13];
  const float* bih = (const float*)d_in[14];
  const float* bhh = (const float*)d_in[15];
  const float* outW = (const float*)d_in[16];
  const float* outb = (const float*)d_in[17];

  float* out_logp = (float*)d_out;                       // [T*B, V]
  float* out_hidden = out_logp + (size_t)T_ * B_ * V_;   // [B, H]
  float* out_attn = out_hidden + (size_t)B_ * H_;        // [T, B, S]

  float* ws = (float*)d_ws;
  float* ah3w = ws;                                      // T*B*A
  float* pmaxw = ah3w + (size_t)T_ * B_ * A_;            // NCB*MROWS
  float* psumw = pmaxw + (size_t)NCB * MROWS;            // NCB*MROWS
  float* lsew = psumw + (size_t)NCB * MROWS;             // MROWS
  float* giXw = lsew + MROWS;                            // T*B*G3 (19.7 MB)
  __hip_bfloat16* hallw = (__hip_bfloat16*)(giXw + (size_t)MROWS * G3); // MROWS*KP
  __hip_bfloat16* wpkw = hallw + (size_t)MROWS * KP;          // (KP/8)*VP*8
  _Float16* ah2hw = (_Float16*)(wpkw + (size_t)(KP / 8) * VP * 8); // B*S*AH2P
  _Float16* W1hw = ah2hw + (size_t)B_ * S_ * AH2P;            // 25*A*8
  _Float16* Wihhw = W1hw + (size_t)25 * A_ * 8;               // 50*G3*8
  _Float16* Whhhw = Wihhw + (size_t)50 * G3 * 8;              // 25*G3*8
  __hip_bfloat16* wepw = (__hip_bfloat16*)(Whhhw + (size_t)25 * G3 * 8); // (KP/8)*NP*8
  __hip_bfloat16* w2pw = wepw + (size_t)(KP / 8) * NP * 8;    // (KP/8)*NP2*8

  k_pack<<<256, 256, 0, stream>>>(W1, Wih, Whh, W3, W2,
                                  W1hw, Wihhw, Whhhw, wepw, w2pw, ah2hw);
  k_genc<<<dim3(1, S_ * B_ / 128), 256, 0, stream>>>(encoder, (const short*)w2pw,
                                                     b2, ah2hw);
  k_gemb<<<dim3(NP / 256, MROWS / 64), 256, 0, stream>>>(tokens, emb, (const short*)wepw,
                                                         bih, b3, giXw, ah3w);

  k_recur<<<B_ + NPK, NTH, 0, stream>>>(hidden0, ah2hw, ah3w, encoder, W1hw, b1, attn_W,
                                        attn_b, Wihhw, Whhhw, bhh, giXw, outW, wpkw,
                                        hallw, out_hidden, out_attn);

  k_big0<<<dim3(NCB, MROWS / 64), 256, 0, stream>>>((const short*)hallw, (const short*)wpkw,
                                                    outb, pmaxw, psumw, out_logp);
  k_lse<<<MROWS / 256, 256, 0, stream>>>(pmaxw, psumw, lsew);
  k_norm<<<MROWS / 4, 256, 0, stream>>>(out_logp, lsew);
}

// Round 22
// 995.529 us; speedup vs baseline: 1.1166x; 1.1166x over previous
//
#include <hip/hip_runtime.h>
#include <hip/hip_bf16.h>
#include <cmath>

constexpr int T_ = 64, B_ = 128, S_ = 128, H_ = 200, E_ = 200, A_ = 100, V_ = 10003;
constexpr int KP = 224;        // padded K (=H/E), multiple of 32
constexpr int VP = 10240;      // padded V, multiple of 256
constexpr int MROWS = T_ * B_; // 8192 rows in the batched GEMMs
constexpr int NCB = VP / 256;  // 40 column-blocks
constexpr int G3 = 3 * H_;     // 600 gate rows
constexpr int EH = E_ + H_;    // 400
constexpr int ELD = 136;       // encLh row stride in f16 (16B-aligned)
constexpr int AH2P = 104;      // padded A for f16 ah2 rows (13 x 8)
constexpr int NP = 768;        // padded col count for [Wih_e | W3] fragment pack
constexpr int NP2 = 128;       // padded col count for W2 fragment pack
constexpr int NTH = 512;       // k_recur block size (proven 128-VGPR config)
constexpr int NPK = 32;        // spare pack blocks appended to k_recur grid

typedef __attribute__((ext_vector_type(8))) short bf16x8;
typedef __attribute__((ext_vector_type(4))) float f32x4;
typedef __attribute__((ext_vector_type(2))) _Float16 h2;
typedef __attribute__((ext_vector_type(8))) _Float16 h8;

#if __has_builtin(__builtin_amdgcn_fdot2)
__device__ __forceinline__ float fdot2f(h2 a, h2 b, float c) {
  return __builtin_amdgcn_fdot2(a, b, c, false);
}
#else
__device__ __forceinline__ float fdot2f(h2 a, h2 b, float c) {
  return c + (float)a[0] * (float)b[0] + (float)a[1] * (float)b[1];
}
#endif

// Depth-5 software-pipelined 200-length dot (R13 proven: fits 128 VGPRs).
__device__ __forceinline__ float dot200p5(const h8* __restrict__ w, int stride,
                                          const h8* __restrict__ x) {
  const h8* p = w;
  h8 w0 = p[0]; p += stride;
  h8 w1 = p[0]; p += stride;
  h8 w2 = p[0]; p += stride;
  h8 w3 = p[0]; p += stride;
  h8 w4 = p[0]; p += stride;
  float a0 = 0.f, a1 = 0.f, a2 = 0.f, a3 = 0.f;
#define DOT_CONSUME(WREG, K)                    \
  {                                             \
    h8 xv = x[K];                               \
    h2 wp[4], xp[4];                            \
    __builtin_memcpy(wp, &WREG, 16);            \
    __builtin_memcpy(xp, &xv, 16);              \
    a0 = fdot2f(wp[0], xp[0], a0);              \
    a1 = fdot2f(wp[1], xp[1], a1);              \
    a2 = fdot2f(wp[2], xp[2], a2);              \
    a3 = fdot2f(wp[3], xp[3], a3);              \
  }
#define DOT_RELOAD(WREG) { WREG = p[0]; p += stride; }
  DOT_CONSUME(w0, 0)  DOT_RELOAD(w0)
  DOT_CONSUME(w1, 1)  DOT_RELOAD(w1)
  DOT_CONSUME(w2, 2)  DOT_RELOAD(w2)
  DOT_CONSUME(w3, 3)  DOT_RELOAD(w3)
  DOT_CONSUME(w4, 4)  DOT_RELOAD(w4)
  DOT_CONSUME(w0, 5)  DOT_RELOAD(w0)
  DOT_CONSUME(w1, 6)  DOT_RELOAD(w1)
  DOT_CONSUME(w2, 7)  DOT_RELOAD(w2)
  DOT_CONSUME(w3, 8)  DOT_RELOAD(w3)
  DOT_CONSUME(w4, 9)  DOT_RELOAD(w4)
  DOT_CONSUME(w0, 10) DOT_RELOAD(w0)
  DOT_CONSUME(w1, 11) DOT_RELOAD(w1)
  DOT_CONSUME(w2, 12) DOT_RELOAD(w2)
  DOT_CONSUME(w3, 13) DOT_RELOAD(w3)
  DOT_CONSUME(w4, 14) DOT_RELOAD(w4)
  DOT_CONSUME(w0, 15) DOT_RELOAD(w0)
  DOT_CONSUME(w1, 16) DOT_RELOAD(w1)
  DOT_CONSUME(w2, 17) DOT_RELOAD(w2)
  DOT_CONSUME(w3, 18) DOT_RELOAD(w3)
  DOT_CONSUME(w4, 19) DOT_RELOAD(w4)
  DOT_CONSUME(w0, 20)
  DOT_CONSUME(w1, 21)
  DOT_CONSUME(w2, 22)
  DOT_CONSUME(w3, 23)
  DOT_CONSUME(w4, 24)
#undef DOT_CONSUME
#undef DOT_RELOAD
  return (a0 + a1) + (a2 + a3);
}

// ---------------- precompute kernels ----------------

// Small f16/bf16 packs needed BEFORE k_recur / k_genc / k_gemb; zero ah2h pad.
__global__ __launch_bounds__(256) void k_pack(const float* __restrict__ W1,
                                              const float* __restrict__ Wih,
                                              const float* __restrict__ Whh,
                                              const float* __restrict__ W3,
                                              const float* __restrict__ W2,
                                              _Float16* __restrict__ W1h,
                                              _Float16* __restrict__ Wihh,
                                              _Float16* __restrict__ Whhh,
                                              __hip_bfloat16* __restrict__ wep,
                                              __hip_bfloat16* __restrict__ w2p,
                                              _Float16* __restrict__ ah2h) {
  const int stride = gridDim.x * blockDim.x;
  const int tid0 = blockIdx.x * blockDim.x + threadIdx.x;
  for (int idx = tid0; idx < 25 * A_ * 8; idx += stride) {
    int kk = idx & 7, a = (idx >> 3) % A_, k8 = idx / (8 * A_);
    W1h[idx] = (_Float16)W1[(size_t)a * H_ + k8 * 8 + kk];
  }
  for (int idx = tid0; idx < 50 * G3 * 8; idx += stride) {
    int kk = idx & 7, n = (idx >> 3) % G3, k8 = idx / (8 * G3);
    Wihh[idx] = (_Float16)Wih[(size_t)n * EH + k8 * 8 + kk];
  }
  for (int idx = tid0; idx < 25 * G3 * 8; idx += stride) {
    int kk = idx & 7, n = (idx >> 3) % G3, k8 = idx / (8 * G3);
    Whhh[idx] = (_Float16)Whh[(size_t)n * H_ + k8 * 8 + kk];
  }
  // WEP: [KP/8][NP][8] bf16 pack of [Wih_e (600) | W3 (100) | pad]
  for (int idx = tid0; idx < (KP / 8) * NP * 8; idx += stride) {
    int kk = idx & 7, c = (idx >> 3) % NP, k8 = idx / (8 * NP);
    int k = k8 * 8 + kk;
    float v = 0.f;
    if (k < E_) {
      if (c < G3) v = Wih[(size_t)c * EH + k];           // xe-half of Wih
      else if (c < G3 + A_) v = W3[(size_t)(c - G3) * E_ + k];
    }
    wep[idx] = __float2bfloat16(v);
  }
  // W2P: [KP/8][NP2][8] bf16 pack of W2 (100 rows)
  for (int idx = tid0; idx < (KP / 8) * NP2 * 8; idx += stride) {
    int kk = idx & 7, c = (idx >> 3) % NP2, k8 = idx / (8 * NP2);
    int k = k8 * 8 + kk;
    float v = (k < H_ && c < A_) ? W2[(size_t)c * H_ + k] : 0.f;
    w2p[idx] = __float2bfloat16(v);
  }
  // zero ah2h pad columns [A_, AH2P)
  for (int idx = tid0; idx < B_ * S_ * (AH2P - A_); idx += stride) {
    int row = idx / (AH2P - A_), col = A_ + idx % (AH2P - A_);
    ah2h[(size_t)row * AH2P + col] = (_Float16)0.f;
  }
}

// MFMA GEMM: ah2h = enc @ W2^T + b2 (f16 out, (b,s)-transposed write).
__global__ __launch_bounds__(256) void k_genc(const float* __restrict__ encoder,
                                              const short* __restrict__ w2p,
                                              const float* __restrict__ b2,
                                              _Float16* __restrict__ ah2h) {
  constexpr int ALD = 232;
  __shared__ __align__(16) __hip_bfloat16 aL[128 * ALD]; // 59.4 KB
  const int tid = threadIdx.x;
  const int w = tid >> 6, l = tid & 63, lm = l & 15, lg = l >> 4;
  const int r0 = blockIdx.y * 128;
  const int rloc = (w >> 1) * 64;
  const int v0 = (w & 1) * 64;

  for (int i = tid; i < 128 * KP; i += 256) {
    int row = i / KP, k = i - row * KP;
    float v = (k < H_) ? encoder[(size_t)(r0 + row) * H_ + k] : 0.f;
    aL[row * ALD + k] = __float2bfloat16(v);
  }
  __syncthreads();

  f32x4 acc[4][4] = {};
#pragma unroll
  for (int kt = 0; kt < KP / 32; ++kt) {
    const int k0 = kt * 32;
    bf16x8 af[4], bfr[4];
#pragma unroll
    for (int wm = 0; wm < 4; ++wm)
      af[wm] = *(const bf16x8*)(aL + (rloc + wm * 16 + lm) * ALD + k0 + lg * 8);
#pragma unroll
    for (int n = 0; n < 4; ++n)
      bfr[n] = *(const bf16x8*)(w2p + ((size_t)((k0 >> 3) + lg) * NP2 + v0 + n * 16 + lm) * 8);
#pragma unroll
    for (int wm = 0; wm < 4; ++wm)
#pragma unroll
      for (int n = 0; n < 4; ++n)
        acc[wm][n] = __builtin_amdgcn_mfma_f32_16x16x32_bf16(af[wm], bfr[n], acc[wm][n], 0, 0, 0);
  }

#pragma unroll
  for (int n = 0; n < 4; ++n) {
    const int vv = v0 + n * 16 + lm;
    if (vv >= A_) continue;
    const float bias = b2[vv];
#pragma unroll
    for (int wm = 0; wm < 4; ++wm) {
#pragma unroll
      for (int j = 0; j < 4; ++j) {
        const int grow = r0 + rloc + wm * 16 + lg * 4 + j; // = s*B + b
        const int bb = grow & (B_ - 1);
        const int ss = grow >> 7;
        ah2h[((size_t)bb * S_ + ss) * AH2P + vv] = (_Float16)(acc[wm][n][j] + bias);
      }
    }
  }
}

// MFMA GEMM over gathered emb rows: [giX | ah3] = emb[tok[r]] @ [Wih_e | W3]^T + bias
__global__ __launch_bounds__(256) void k_gemb(const int* __restrict__ tokens,
                                              const float* __restrict__ emb,
                                              const short* __restrict__ wep,
                                              const float* __restrict__ bih,
                                              const float* __restrict__ b3,
                                              float* __restrict__ giX,
                                              float* __restrict__ ah3) {
  constexpr int ALD = 232;
  __shared__ __align__(16) __hip_bfloat16 aL[64 * ALD];
  __shared__ int tokL[64];
  const int tid = threadIdx.x;
  const int w = tid >> 6, l = tid & 63, lm = l & 15, lg = l >> 4;
  const int r0 = blockIdx.y * 64;
  const int v0 = blockIdx.x * 256 + w * 64;

  if (tid < 64) tokL[tid] = tokens[r0 + tid];
  __syncthreads();
  for (int i = tid; i < 64 * KP; i += 256) {
    int row = i / KP, k = i - row * KP;
    float v = (k < E_) ? emb[(size_t)tokL[row] * E_ + k] : 0.f;
    aL[row * ALD + k] = __float2bfloat16(v);
  }
  __syncthreads();

  f32x4 acc[4][4] = {};
#pragma unroll
  for (int kt = 0; kt < KP / 32; ++kt) {
    const int k0 = kt * 32;
    bf16x8 af[4], bfr[4];
#pragma unroll
    for (int wm = 0; wm < 4; ++wm)
      af[wm] = *(const bf16x8*)(aL + (wm * 16 + lm) * ALD + k0 + lg * 8);
#pragma unroll
    for (int n = 0; n < 4; ++n)
      bfr[n] = *(const bf16x8*)(wep + ((size_t)((k0 >> 3) + lg) * NP + v0 + n * 16 + lm) * 8);
#pragma unroll
    for (int wm = 0; wm < 4; ++wm)
#pragma unroll
      for (int n = 0; n < 4; ++n)
        acc[wm][n] = __builtin_amdgcn_mfma_f32_16x16x32_bf16(af[wm], bfr[n], acc[wm][n], 0, 0, 0);
  }

#pragma unroll
  for (int n = 0; n < 4; ++n) {
    const int vv = v0 + n * 16 + lm;
    const bool isGi = vv < G3;
    const bool isA3 = !isGi && vv < G3 + A_;
    const float bias = isGi ? bih[vv] : (isA3 ? b3[vv - G3] : 0.f);
#pragma unroll
    for (int wm = 0; wm < 4; ++wm) {
#pragma unroll
      for (int j = 0; j < 4; ++j) {
        const int row = r0 + wm * 16 + lg * 4 + j;
        const float val = acc[wm][n][j] + bias;
        if (isGi) giX[(size_t)row * G3 + vv] = val;
        else if (isA3) ah3[(size_t)row * A_ + (vv - G3)] = val;
      }
    }
  }
}

// ---------------- persistent recurrence kernel (R15 compute, 512 threads) ----
__global__ __launch_bounds__(NTH) void k_recur(const float* __restrict__ hidden0,
                                               const _Float16* __restrict__ ah2h,
                                               const float* __restrict__ ah3,
                                               const float* __restrict__ encoder,
                                               const _Float16* __restrict__ W1h,
                                               const float* __restrict__ b1,
                                               const float* __restrict__ attn_W,
                                               const float* __restrict__ attn_b,
                                               const _Float16* __restrict__ Wihh,
                                               const _Float16* __restrict__ Whhh,
                                               const float* __restrict__ bhh,
                                               const float* __restrict__ giX,
                                               const float* __restrict__ outW,
                                               __hip_bfloat16* __restrict__ wpk,
                                               __hip_bfloat16* __restrict__ hall,
                                               float* __restrict__ out_hidden,
                                               float* __restrict__ out_attn) {
  __shared__ __align__(16) _Float16 encLh[H_ * ELD]; // [h][s] f16, 54.4 KB
  __shared__ __align__(16) h2 h16[100];
  __shared__ __align__(16) h2 xch[100];
  __shared__ __align__(16) h2 aLh[64];
  __shared__ float s1[AH2P];
  __shared__ float aW[AH2P];
  __shared__ float red[8];
  __shared__ float giL[G3];    // step-t giX row, prefetched in phase 3
  __shared__ float part[1200]; // [0,600): h.Whh | [600,1200): xc.Wih_c

  const int b = blockIdx.x, tid = threadIdx.x;
  const int lane = tid & 63;

  if (b >= B_) {
    const int pt = (b - B_) * NTH + tid;
    const int pstride = NPK * NTH;
    const int total = (KP / 8) * VP * 8;
    for (int idx = pt; idx < total; idx += pstride) {
      int kk = idx & 7;
      int v = (idx >> 3) % VP;
      int kb = idx / (8 * VP);
      int k = kb * 8 + kk;
      float val = (k < H_ && v < V_) ? outW[(size_t)v * H_ + k] : 0.f;
      wpk[idx] = __float2bfloat16(val);
    }
    const __hip_bfloat16 z = __float2bfloat16(0.f);
    for (int idx = pt; idx < MROWS * (KP - H_); idx += pstride) {
      int row = idx / (KP - H_), col = H_ + idx % (KP - H_);
      hall[(size_t)row * KP + col] = z;
    }
    return;
  }

  // ---- one-time init ----
  for (int i = tid; i < S_ * H_; i += NTH) {
    int s = i / H_, h = i - s * H_;
    encLh[h * ELD + s] = (_Float16)encoder[((size_t)s * B_ + b) * H_ + h];
  }
  float hreg = 0.f, bhr = 0.f, bhz = 0.f, bhn = 0.f;
  if (tid < H_) {
    hreg = hidden0[b * H_ + tid];
    bhr = bhh[tid]; bhz = bhh[200 + tid]; bhn = bhh[400 + tid];
  }
  if (tid < 100) {
    h2 v;
    v[0] = (_Float16)hidden0[b * H_ + 2 * tid];
    v[1] = (_Float16)hidden0[b * H_ + 2 * tid + 1];
    h16[tid] = v;
  }
  for (int i = tid; i < AH2P; i += NTH) {
    aW[i] = (i < A_) ? attn_W[i] : 0.f;
    s1[i] = 0.f;
  }
  h8 ah2row[13]; // b-row of ah2 at s=tid, t-invariant; registers (tid<128 only)
  if (tid < S_) {
    const h8* src = (const h8*)(ah2h + ((size_t)b * S_ + tid) * AH2P);
#pragma unroll
    for (int r = 0; r < 13; ++r) ah2row[r] = src[r];
  }
  const float ab = attn_b[0];
  __syncthreads();

  const h8* W1h8 = (const h8*)W1h;
  const h8* Wihc8 = (const h8*)Wihh + (size_t)25 * G3; // xc-half: k8 in [25,50)
  const h8* Whhh8 = (const h8*)Whhh;

  for (int t = 0; t < T_; ++t) {
    const h8* xs = (const h8*)h16;
    // ---- phase 1: 700 units = 100 s1-dots + 600 gh-dots (interleaved u-loop)
    for (int u = tid; u < 700; u += NTH) {
      if (u < 100) {
        const float ah3A = ah3[((size_t)t * B_ + b) * A_ + u]; // early loads
        const float b1A = b1[u];
        s1[u] = dot200p5(W1h8 + u, A_, xs) + b1A + ah3A;
      } else {
        const int g = u - 100;
        part[g] = dot200p5(Whhh8 + g, G3, xs);
      }
    }
    __syncthreads();

    // ---- phase 2: relu-attn logits + flash-merged softmax (tid<128)
    float evw = 0.f;
    const int w01 = tid >> 6;
    if (tid < S_) {
      float acc = ab;
#pragma unroll
      for (int r = 0; r < 13; ++r) {
        h8 w = ah2row[r];
#pragma unroll
        for (int j = 0; j < 8; ++j) {
          const int a = r * 8 + j;
          acc += fmaxf(s1[a] + (float)w[j], 0.f) * aW[a];
        }
      }
      float m = acc;
#pragma unroll
      for (int off = 32; off > 0; off >>= 1) m = fmaxf(m, __shfl_xor(m, off, 64));
      evw = expf(acc - m);
      float sm = evw;
#pragma unroll
      for (int off = 32; off > 0; off >>= 1) sm += __shfl_xor(sm, off, 64);
      if (lane == 0) { red[w01] = m; red[4 + w01] = sm; }
    }
    __syncthreads();
    if (tid < S_) {
      const float m0 = red[0], m1 = red[1];
      const float M = fmaxf(m0, m1);
      const float SS = red[4] * expf(m0 - M) + red[5] * expf(m1 - M);
      const float av = evw * expf((w01 ? m1 : m0) - M) / SS;
      out_attn[((size_t)t * B_ + b) * S_ + tid] = av;
      const float avn = __shfl_xor(av, 1, 64);
      if ((tid & 1) == 0) {
        h2 v; v[0] = (_Float16)av; v[1] = (_Float16)avn;
        aLh[tid >> 1] = v;
      }
    }
    __syncthreads();

    // ---- phase 3: ctx (tid<200) || giX prefetch -> LDS (tid>=200)
    if (tid < H_) {
      const h8* er = (const h8*)(encLh + tid * ELD);
      float c0 = 0.f, c1 = 0.f, c2 = 0.f, c3 = 0.f;
#pragma unroll
      for (int k8 = 0; k8 < 16; ++k8) {
        h8 evv = er[k8];
        h2 ep[4];
        __builtin_memcpy(ep, &evv, 16);
        c0 = fdot2f(ep[0], aLh[4 * k8 + 0], c0);
        c1 = fdot2f(ep[1], aLh[4 * k8 + 1], c1);
        c2 = fdot2f(ep[2], aLh[4 * k8 + 2], c2);
        c3 = fdot2f(ep[3], aLh[4 * k8 + 3], c3);
      }
      const float c = (c0 + c1) + (c2 + c3);
      const float cn = __shfl_xor(c, 1, 64);
      if ((tid & 1) == 0) {
        h2 v; v[0] = (_Float16)c; v[1] = (_Float16)cn;
        xch[tid >> 1] = v;
      }
    } else {
      const int j = tid - 200; // 312 threads cover 300 float2
      if (j < 300) {
        float2 g2 = ((const float2*)(giX + ((size_t)t * B_ + b) * G3))[j];
        giL[2 * j] = g2.x;
        giL[2 * j + 1] = g2.y;
      }
    }
    __syncthreads();

    // ---- phase 4: gi_xc (600 units, interleaved u-loop)
    {
      const h8* xc8 = (const h8*)xch;
      for (int u = tid; u < 600; u += NTH) {
        part[600 + u] = dot200p5(Wihc8 + u, G3, xc8);
      }
    }
    __syncthreads();

    // ---- phase 5: gates + h update (tid<200); giX partials from LDS
    if (tid < H_) {
      const int n = tid;
      const float gir = giL[n] + part[600 + n];
      const float giz = giL[200 + n] + part[800 + n];
      const float gin = giL[400 + n] + part[1000 + n];
      const float ghr = part[n] + bhr;
      const float ghz = part[200 + n] + bhz;
      const float ghn = part[400 + n] + bhn;
      const float r = 1.f / (1.f + expf(-(gir + ghr)));
      const float z = 1.f / (1.f + expf(-(giz + ghz)));
      const float nn = tanhf(gin + r * ghn);
      const float hv = (1.f - z) * nn + z * hreg;
      hreg = hv;
      hall[((size_t)t * B_ + b) * KP + n] = __float2bfloat16(hv);
      const float hn2 = __shfl_xor(hv, 1, 64);
      if ((n & 1) == 0) {
        h2 v; v[0] = (_Float16)hv; v[1] = (_Float16)hn2;
        h16[n >> 1] = v;
      }
      if (t == T_ - 1) out_hidden[b * H_ + n] = hv;
    }
    __syncthreads();
  }
}

// ---------------- batched output GEMM + log-softmax ----------------
__global__ __launch_bounds__(256) void k_big0(const short* __restrict__ hb,
                                              const short* __restrict__ wpk,
                                              const float* __restrict__ outb,
                                              float* __restrict__ pmax,
                                              float* __restrict__ psum) {
  const int tid = threadIdx.x;
  const int w = tid >> 6, l = tid & 63;
  const int lm = l & 15, lg = l >> 4;
  const int r0 = blockIdx.y * 64;
  const int v0 = blockIdx.x * 256 + w * 64;

  f32x4 acc[4][4] = {};
#pragma unroll
  for (int kt = 0; kt < KP / 32; ++kt) {
    const int k0 = kt * 32;
    bf16x8 af[4], bfr[4];
#pragma unroll
    for (int wm = 0; wm < 4; ++wm)
      af[wm] = *(const bf16x8*)(hb + (size_t)(r0 + wm * 16 + lm) * KP + k0 + lg * 8);
#pragma unroll
    for (int n = 0; n < 4; ++n)
      bfr[n] = *(const bf16x8*)(wpk + ((size_t)((k0 >> 3) + lg) * VP + v0 + n * 16 + lm) * 8);
#pragma unroll
    for (int wm = 0; wm < 4; ++wm)
#pragma unroll
      for (int n = 0; n < 4; ++n)
        acc[wm][n] = __builtin_amdgcn_mfma_f32_16x16x32_bf16(af[wm], bfr[n], acc[wm][n], 0, 0, 0);
  }

  int vv[4]; float bias[4]; bool val[4];
#pragma unroll
  for (int n = 0; n < 4; ++n) {
    vv[n] = v0 + n * 16 + lm;
    val[n] = vv[n] < V_;
    bias[n] = val[n] ? outb[vv[n]] : 0.f;
  }

  __shared__ float smax[4][64], ssum[4][64];
#pragma unroll
  for (int wm = 0; wm < 4; ++wm) {
#pragma unroll
    for (int j = 0; j < 4; ++j) {
      float mv = -INFINITY;
#pragma unroll
      for (int n = 0; n < 4; ++n)
        if (val[n]) mv = fmaxf(mv, acc[wm][n][j] + bias[n]);
      for (int off = 8; off > 0; off >>= 1) mv = fmaxf(mv, __shfl_xor(mv, off, 64));
      float sv = 0.f;
#pragma unroll
      for (int n = 0; n < 4; ++n)
        if (val[n]) sv += expf(acc[wm][n][j] + bias[n] - mv);
      for (int off = 8; off > 0; off >>= 1) sv += __shfl_xor(sv, off, 64);
      if (lm == 0) {
        smax[w][wm * 16 + lg * 4 + j] = mv;
        ssum[w][wm * 16 + lg * 4 + j] = sv;
      }
    }
  }
  __syncthreads();
  if (tid < 64) {
    float mv = -INFINITY;
    for (int ww = 0; ww < 4; ++ww) mv = fmaxf(mv, smax[ww][tid]);
    float sv = 0.f;
    for (int ww = 0; ww < 4; ++ww) {
      float sw = ssum[ww][tid];
      if (sw > 0.f) sv += expf(smax[ww][tid] - mv) * sw;
    }
    pmax[(size_t)blockIdx.x * MROWS + r0 + tid] = mv;
    psum[(size_t)blockIdx.x * MROWS + r0 + tid] = sv;
  }
}

__global__ __launch_bounds__(256) void k_lse(const float* __restrict__ pmax,
                                             const float* __restrict__ psum,
                                             float* __restrict__ lse) {
  const int r = blockIdx.x * 256 + threadIdx.x;
  float mv = -INFINITY;
  for (int c = 0; c < NCB; ++c) mv = fmaxf(mv, pmax[(size_t)c * MROWS + r]);
  float sv = 0.f;
  for (int c = 0; c < NCB; ++c) {
    float sw = psum[(size_t)c * MROWS + r];
    if (sw > 0.f) sv += expf(pmax[(size_t)c * MROWS + r] - mv) * sw;
  }
  lse[r] = mv + logf(sv);
}

// pass 1: recompute GEMM; epilogue stages rows in LDS so global stores are
// lane-consecutive (fully coalesced 256B wave stores of the 328 MB output).
__global__ __launch_bounds__(256) void k_big1(const short* __restrict__ hb,
                                              const short* __restrict__ wpk,
                                              const float* __restrict__ outb,
                                              const float* __restrict__ lse,
                                              float* __restrict__ out_logp) {
  const int tid = threadIdx.x;
  const int w = tid >> 6, l = tid & 63;
  const int lm = l & 15, lg = l >> 4;
  const int r0 = blockIdx.y * 64;
  const int v0c = blockIdx.x * 256;
  const int v0 = v0c + w * 64;

  __shared__ float lseL[64];
  __shared__ float tr[32][260]; // 33.3 KB row-staging tile (pad 260)
  if (tid < 64) lseL[tid] = lse[r0 + tid];

  f32x4 acc[4][4] = {};
#pragma unroll
  for (int kt = 0; kt < KP / 32; ++kt) {
    const int k0 = kt * 32;
    bf16x8 af[4], bfr[4];
#pragma unroll
    for (int wm = 0; wm < 4; ++wm)
      af[wm] = *(const bf16x8*)(hb + (size_t)(r0 + wm * 16 + lm) * KP + k0 + lg * 8);
#pragma unroll
    for (int n = 0; n < 4; ++n)
      bfr[n] = *(const bf16x8*)(wpk + ((size_t)((k0 >> 3) + lg) * VP + v0 + n * 16 + lm) * 8);
#pragma unroll
    for (int wm = 0; wm < 4; ++wm)
#pragma unroll
      for (int n = 0; n < 4; ++n)
        acc[wm][n] = __builtin_amdgcn_mfma_f32_16x16x32_bf16(af[wm], bfr[n], acc[wm][n], 0, 0, 0);
  }

  float bias[4];
#pragma unroll
  for (int n = 0; n < 4; ++n) {
    const int vv = v0 + n * 16 + lm;
    bias[n] = (vv < V_) ? outb[vv] : 0.f;
  }

  // two 32-row halves: stage acc+bias into LDS, then coalesced row-major write
#pragma unroll
  for (int half = 0; half < 2; ++half) {
    __syncthreads();
#pragma unroll
    for (int wmi = 0; wmi < 2; ++wmi) {
      const int wm = half * 2 + wmi;
#pragma unroll
      for (int n = 0; n < 4; ++n) {
        const int col = w * 64 + n * 16 + lm; // 0..255 in block window
#pragma unroll
        for (int j = 0; j < 4; ++j) {
          tr[wmi * 16 + lg * 4 + j][col] = acc[wm][n][j] + bias[n];
        }
      }
    }
    __syncthreads();
    // 32 rows x 256 cols; lane-consecutive cols -> coalesced scalar stores
    const int lw = tid & 63;
    const int wv = tid >> 6;
    for (int rr = wv; rr < 32; rr += 4) {
      const int grow = r0 + half * 32 + rr;
      const float ls = lseL[half * 32 + rr];
      float* dst = out_logp + (size_t)grow * V_;
#pragma unroll
      for (int cc = 0; cc < 4; ++cc) {
        const int col = cc * 64 + lw;
        const int vv = v0c + col;
        if (vv < V_) dst[vv] = tr[rr][col] - ls;
      }
    }
  }
}

// ---------------- host launch ----------------

extern "C" void kernel_launch(void* const* d_in, const int* in_sizes, int n_in,
                              void* d_out, int out_size, void* d_ws, size_t ws_size,
                              hipStream_t stream) {
  (void)in_sizes; (void)n_in; (void)out_size; (void)ws_size;
  const int* tokens = (const int*)d_in[0];
  const float* hidden0 = (const float*)d_in[1];
  const float* encoder = (const float*)d_in[2];
  const float* emb = (const float*)d_in[3];
  const float* W1 = (const float*)d_in[4];
  const float* b1 = (const float*)d_in[5];
  const float* W2 = (const float*)d_in[6];
  const float* b2 = (const float*)d_in[7];
  const float* W3 = (const float*)d_in[8];
  const float* b3 = (const float*)d_in[9];
  const float* attn_W = (const float*)d_in[10];
  const float* attn_b = (const float*)d_in[11];
  const float* Wih = (const float*)d_in[12];
  const float* Whh = (const float*)d_in[13];
  const float* bih = (const float*)d_in[14];
  const float* bhh = (const float*)d_in[15];
  const float* outW = (const float*)d_in[16];
  const float* outb = (const float*)d_in[17];

  float* out_logp = (float*)d_out;                       // [T*B, V]
  float* out_hidden = out_logp + (size_t)T_ * B_ * V_;   // [B, H]
  float* out_attn = out_hidden + (size_t)B_ * H_;        // [T, B, S]

  float* ws = (float*)d_ws;
  float* ah3w = ws;                                      // T*B*A
  float* pmaxw = ah3w + (size_t)T_ * B_ * A_;            // NCB*MROWS
  float* psumw = pmaxw + (size_t)NCB * MROWS;            // NCB*MROWS
  float* lsew = psumw + (size_t)NCB * MROWS;             // MROWS
  float* giXw = lsew + MROWS;                            // T*B*G3 (19.7 MB)
  __hip_bfloat16* hallw = (__hip_bfloat16*)(giXw + (size_t)MROWS * G3); // MROWS*KP
  __hip_bfloat16* wpkw = hallw + (size_t)MROWS * KP;          // (KP/8)*VP*8
  _Float16* ah2hw = (_Float16*)(wpkw + (size_t)(KP / 8) * VP * 8); // B*S*AH2P
  _Float16* W1hw = ah2hw + (size_t)B_ * S_ * AH2P;            // 25*A*8
  _Float16* Wihhw = W1hw + (size_t)25 * A_ * 8;               // 50*G3*8
  _Float16* Whhhw = Wihhw + (size_t)50 * G3 * 8;              // 25*G3*8
  __hip_bfloat16* wepw = (__hip_bfloat16*)(Whhhw + (size_t)25 * G3 * 8); // (KP/8)*NP*8
  __hip_bfloat16* w2pw = wepw + (size_t)(KP / 8) * NP * 8;    // (KP/8)*NP2*8

  k_pack<<<256, 256, 0, stream>>>(W1, Wih, Whh, W3, W2,
                                  W1hw, Wihhw, Whhhw, wepw, w2pw, ah2hw);
  k_genc<<<dim3(1, S_ * B_ / 128), 256, 0, stream>>>(encoder, (const short*)w2pw,
                                                     b2, ah2hw);
  k_gemb<<<dim3(NP / 256, MROWS / 64), 256, 0, stream>>>(tokens, emb, (const short*)wepw,
                                                         bih, b3, giXw, ah3w);

  k_recur<<<B_ + NPK, NTH, 0, stream>>>(hidden0, ah2hw, ah3w, encoder, W1hw, b1, attn_W,
                                        attn_b, Wihhw, Whhhw, bhh, giXw, outW, wpkw,
                                        hallw, out_hidden, out_attn);

  k_big0<<<dim3(NCB, MROWS / 64), 256, 0, stream>>>((const short*)hallw, (const short*)wpkw,
                                                    outb, pmaxw, psumw);
  k_lse<<<MROWS / 256, 256, 0, stream>>>(pmaxw, psumw, lsew);
  k_big1<<<dim3(NCB, MROWS / 64), 256, 0, stream>>>((const short*)hallw, (const short*)wpkw,
                                                    outb, lsew, out_logp);
}